// Round 5
// baseline (309.087 us; speedup 1.0000x reference)
//
#include <hip/hip_runtime.h>
#include <cmath>

// Problem constants (fixed by setup_inputs): B=2, C=1, W=64, H=1024, d=32, WIN=32
#define H_DIM 1024
#define DCH 32
#define WINR 32
#define TQ 256
#define HALO (TQ + 2*WINR)      // 320 staged positions per tile
#define NBLK 512                // 128 rows * 4 tiles

__device__ __forceinline__ float gelu_f(float v) {
    // exact GELU: 0.5*v*(1+erf(v/sqrt(2)))
    return 0.5f * v * (1.0f + erff(v * 0.70710678118654752440f));
}

// float4-chunk XOR swizzle: conflict-free strided writes, uniform reads unaffected
__device__ __forceinline__ int swz(int p, int c) { return p * 8 + (c ^ (p & 7)); }

__device__ __forceinline__ void matvec32(const float* __restrict__ w,
                                         const float zv[DCH], float out[DCH]) {
    // out[e] = sum_d w[e*32+d] * zv[d]; w accesses are wave-uniform -> s_loads
    #pragma unroll
    for (int e = 0; e < DCH; ++e) {
        const float* wr = w + e * DCH;
        float a0 = 0.f, a1 = 0.f, a2 = 0.f, a3 = 0.f;
        #pragma unroll
        for (int d = 0; d < DCH; d += 4) {
            a0 = fmaf(zv[d+0], wr[d+0], a0);
            a1 = fmaf(zv[d+1], wr[d+1], a1);
            a2 = fmaf(zv[d+2], wr[d+2], a2);
            a3 = fmaf(zv[d+3], wr[d+3], a3);
        }
        out[e] = (a0 + a1) + (a2 + a3);
    }
}

__device__ __forceinline__ void write_row(float* buf, int p, const float r[DCH]) {
    #pragma unroll
    for (int c = 0; c < 8; ++c)
        ((float4*)buf)[swz(p, c)] =
            make_float4(r[4*c+0], r[4*c+1], r[4*c+2], r[4*c+3]);
}

// ---------------------------------------------------------------- K1: x partial sums (GN1 stats; feat = x*w_in since C==1)
__global__ __launch_bounds__(256) void k_xstats(const float* __restrict__ x,
                                                double* __restrict__ part) { // [16][2]
    __shared__ double red[8];
    const int b = blockIdx.x;            // 16 blocks, 8 rows each
    const int t = threadIdx.x;
    const float4* px = (const float4*)(x + (size_t)b * 8192);
    double s = 0.0, s2 = 0.0;
    #pragma unroll
    for (int i = 0; i < 8; ++i) {
        float4 v = px[i * 256 + t];
        s  += (double)v.x + (double)v.y + (double)v.z + (double)v.w;
        s2 += (double)v.x*v.x + (double)v.y*v.y + (double)v.z*v.z + (double)v.w*v.w;
    }
    #pragma unroll
    for (int o = 32; o; o >>= 1) { s += __shfl_down(s, o); s2 += __shfl_down(s2, o); }
    if ((t & 63) == 0) { red[(t>>6)*2] = s; red[(t>>6)*2+1] = s2; }
    __syncthreads();
    if (t == 0) {
        part[b*2+0] = red[0]+red[2]+red[4]+red[6];
        part[b*2+1] = red[1]+red[3]+red[5]+red[7];
    }
}

// ---------------------------------------------------------------- K2: fused z->QKV->banded attention->residual
// grid = 512 blocks (128 rows x 4 tiles), 256 threads. LDS 80 KB -> 2 blocks/CU.
__global__ __launch_bounds__(256, 2) void k_main(
    const float* __restrict__ x,
    const float* __restrict__ w_in,
    const float* __restrict__ w_q,
    const float* __restrict__ w_k,
    const float* __restrict__ w_v,
    const float* __restrict__ gn_w,
    const float* __restrict__ gn_b,
    const float* __restrict__ gammap,
    const double* __restrict__ xpart,    // [16][2]
    double* __restrict__ gn2part,        // [512][2]
    float* __restrict__ out_pre)         // [128][1024][32]
{
    __shared__ float ks[HALO * DCH];     // 40 KB
    __shared__ float vs[HALO * DCH];     // 40 KB

    const int t     = threadIdx.x;
    const int bid   = blockIdx.x;
    const int row   = bid >> 2;
    const int tile  = bid & 3;
    const int batch = row >> 6;
    const int h0    = tile * TQ;
    const int g0    = h0 - WINR;

    // ---- GN1 stats from per-block x partials (uniform s_loads) ----
    double Sx = 0.0, Sx2 = 0.0;
    const double* bp = xpart + batch * 16;
    #pragma unroll
    for (int i = 0; i < 8; ++i) { Sx += bp[2*i]; Sx2 += bp[2*i+1]; }
    float sw = 0.f, sw2 = 0.f;
    #pragma unroll
    for (int d = 0; d < DCH; ++d) { float w = w_in[d]; sw += w; sw2 += w*w; }
    const double n1   = 2097152.0;                    // 32*64*1024
    const double mu1d = (double)sw * Sx / n1;
    const double var1 = (double)sw2 * Sx2 / n1 - mu1d * mu1d;
    const float  mu1  = (float)mu1d;
    const float  rstd1 = (float)(1.0 / sqrt(var1 + 1e-5));

    // z = gelu(x * ca[d] + cb[d])
    float ca[DCH], cb[DCH];
    #pragma unroll
    for (int d = 0; d < DCH; ++d) {
        float a = rstd1 * gn_w[d];
        ca[d] = w_in[d] * a;
        cb[d] = gn_b[d] - mu1 * a;
    }

    const float* xrow = x + (size_t)row * H_DIM;

    // ---- staging: thread t owns position p1 = t+32 (h = h0+t, always valid) ----
    const float xq = xrow[h0 + t];
    float q[DCH];
    {
        float zv[DCH];
        #pragma unroll
        for (int d = 0; d < DCH; ++d) zv[d] = gelu_f(fmaf(xq, ca[d], cb[d]));
        float kr[DCH], vr[DCH];
        matvec32(w_k, zv, kr);
        matvec32(w_v, zv, vr);
        write_row(ks, t + WINR, kr);
        write_row(vs, t + WINR, vr);
        matvec32(w_q, zv, q);
        #pragma unroll
        for (int e = 0; e < DCH; ++e) q[e] *= 0.17677669529663688f; // 1/sqrt(32)
    }
    // halo positions 0..31 and 288..319: wave 0 only (waves 1-3 skip via execz)
    if (t < 64) {
        const int p0 = (t < 32) ? t : (256 + t);
        const int h  = g0 + p0;
        const float xv = ((unsigned)h < H_DIM) ? xrow[h] : 0.f;
        float zv[DCH];
        #pragma unroll
        for (int d = 0; d < DCH; ++d) zv[d] = gelu_f(fmaf(xv, ca[d], cb[d]));
        float kr[DCH], vr[DCH];
        matvec32(w_k, zv, kr);
        matvec32(w_v, zv, vr);
        write_row(ks, p0, kr);
        write_row(vs, p0, vr);
    }
    __syncthreads();

    // ---- attention: wave-uniform key broadcast, lane = query ----
    const int lane  = t & 63;
    const int wid   = t >> 6;
    const int pbase = wid * 64;          // wave's first key slot
    const int jbase = g0 + pbase;        // global h of that slot

    float m = -3.0e38f, l = 0.f;
    float o[DCH];
    #pragma unroll
    for (int d = 0; d < DCH; ++d) o[d] = 0.f;

    #pragma unroll 2
    for (int kk = 0; kk < 128; ++kk) {
        const int p  = pbase + kk;       // wave-uniform LDS row
        const int pm = p & 7;
        const float4* kb = (const float4*)ks + p * 8;
        float a0 = 0.f, a1 = 0.f, a2 = 0.f, a3 = 0.f;
        #pragma unroll
        for (int c = 0; c < 8; ++c) {
            float4 k4 = kb[c ^ pm];      // uniform address: broadcast read
            a0 = fmaf(q[4*c+0], k4.x, a0);
            a1 = fmaf(q[4*c+1], k4.y, a1);
            a2 = fmaf(q[4*c+2], k4.z, a2);
            a3 = fmaf(q[4*c+3], k4.w, a3);
        }
        const float s = (a0 + a1) + (a2 + a3);
        const bool valid = ((unsigned)(kk - lane) <= 64u) &&
                           ((unsigned)(jbase + kk) < (unsigned)H_DIM);
        const float se = valid ? s : -3.0e38f;
        if (__any(se > m + 8.0f)) {      // defer-max: rescale only on real growth
            const float mn = fmaxf(m, se);
            const float corr = __expf(m - mn);
            l *= corr;
            #pragma unroll
            for (int d = 0; d < DCH; ++d) o[d] *= corr;
            m = mn;
        }
        const float pw = valid ? __expf(se - m) : 0.f;   // bounded by e^8
        l += pw;
        const float4* vb = (const float4*)vs + p * 8;
        #pragma unroll
        for (int c = 0; c < 8; ++c) {
            float4 v4 = vb[c ^ pm];      // broadcast read
            o[4*c+0] = fmaf(pw, v4.x, o[4*c+0]);
            o[4*c+1] = fmaf(pw, v4.y, o[4*c+1]);
            o[4*c+2] = fmaf(pw, v4.z, o[4*c+2]);
            o[4*c+3] = fmaf(pw, v4.w, o[4*c+3]);
        }
    }
    const float inv = 1.0f / l;

    // ---- epilogue: out_pre = feat + gamma*o, GN2 per-block partials ----
    const float gamma = gammap[0];
    float so = 0.f, so2 = 0.f;
    float* op = out_pre + ((size_t)row * H_DIM + (h0 + t)) * DCH;
    #pragma unroll
    for (int c = 0; c < 8; ++c) {
        float4 wi4 = ((const float4*)w_in)[c];
        float4 r;
        r.x = fmaf(gamma, o[4*c+0] * inv, xq * wi4.x);
        r.y = fmaf(gamma, o[4*c+1] * inv, xq * wi4.y);
        r.z = fmaf(gamma, o[4*c+2] * inv, xq * wi4.z);
        r.w = fmaf(gamma, o[4*c+3] * inv, xq * wi4.w);
        ((float4*)op)[c] = r;
        so  += r.x + r.y + r.z + r.w;
        so2 += r.x*r.x + r.y*r.y + r.z*r.z + r.w*r.w;
    }
    double ds = (double)so, ds2 = (double)so2;
    #pragma unroll
    for (int ofs = 32; ofs; ofs >>= 1) {
        ds  += __shfl_down(ds, ofs);
        ds2 += __shfl_down(ds2, ofs);
    }
    __syncthreads();                      // all LDS attention reads done
    double* red = (double*)ks;            // reuse LDS (no extra static shared!)
    if (lane == 0) { red[wid*2] = ds; red[wid*2+1] = ds2; }
    __syncthreads();
    if (t == 0) {
        gn2part[bid*2+0] = red[0]+red[2]+red[4]+red[6];
        gn2part[bid*2+1] = red[1]+red[3]+red[5]+red[7];
    }
}

// ---------------------------------------------------------------- K3: GN2 + gelu + out-projection
__global__ __launch_bounds__(256) void k_out(
    const float* __restrict__ out_pre,
    const float* __restrict__ w_out,
    const float* __restrict__ gn_w,
    const float* __restrict__ gn_b,
    const double* __restrict__ gn2part,  // [512][2]
    float* __restrict__ outp)
{
    __shared__ double red[8];
    const int t   = threadIdx.x;
    const int bid = blockIdx.x;
    const int batch = bid >> 8;          // uniform per block

    // reduce this batch's 256 partial pairs across the block
    const double* gp = gn2part + (size_t)batch * 512;
    double ds = gp[2*t], ds2 = gp[2*t+1];
    #pragma unroll
    for (int ofs = 32; ofs; ofs >>= 1) {
        ds  += __shfl_down(ds, ofs);
        ds2 += __shfl_down(ds2, ofs);
    }
    if ((t & 63) == 0) { red[(t>>6)*2] = ds; red[(t>>6)*2+1] = ds2; }
    __syncthreads();
    const double S  = red[0]+red[2]+red[4]+red[6];
    const double S2 = red[1]+red[3]+red[5]+red[7];
    const double n2 = 2097152.0;
    const double mu = S / n2;
    const double var = S2 / n2 - mu * mu;
    const float muf  = (float)mu;
    const float rstd = (float)(1.0 / sqrt(var + 1e-5));

    const int pix = bid * 256 + t;
    const float4* ip = (const float4*)(out_pre + (size_t)pix * DCH);
    float acc_o = 0.f;
    #pragma unroll
    for (int c = 0; c < 8; ++c) {
        float4 v  = ip[c];
        float4 gw = ((const float4*)gn_w)[c];
        float4 gb = ((const float4*)gn_b)[c];
        float4 wo = ((const float4*)w_out)[c];
        acc_o += gelu_f((v.x - muf) * rstd * gw.x + gb.x) * wo.x;
        acc_o += gelu_f((v.y - muf) * rstd * gw.y + gb.y) * wo.y;
        acc_o += gelu_f((v.z - muf) * rstd * gw.z + gb.z) * wo.z;
        acc_o += gelu_f((v.w - muf) * rstd * gw.w + gb.w) * wo.w;
    }
    outp[pix] = acc_o;
}

// ---------------------------------------------------------------- launch
extern "C" void kernel_launch(void* const* d_in, const int* in_sizes, int n_in,
                              void* d_out, int out_size, void* d_ws, size_t ws_size,
                              hipStream_t stream) {
    const float* x     = (const float*)d_in[0];
    const float* w_in  = (const float*)d_in[1];
    const float* w_q   = (const float*)d_in[2];
    const float* w_k   = (const float*)d_in[3];
    const float* w_v   = (const float*)d_in[4];
    const float* w_out = (const float*)d_in[5];
    const float* gn_w  = (const float*)d_in[6];
    const float* gn_b  = (const float*)d_in[7];
    const float* gamma = (const float*)d_in[8];

    double* xpart   = (double*)d_ws;                          // 32 doubles
    double* gn2part = (double*)((char*)d_ws + 256);           // 1024 doubles
    float*  out_pre = (float*)((char*)d_ws + 8448);           // 16.78 MB
    float*  outp    = (float*)d_out;

    k_xstats<<<dim3(16),   dim3(256), 0, stream>>>(x, xpart);
    k_main  <<<dim3(NBLK), dim3(256), 0, stream>>>(
        x, w_in, w_q, w_k, w_v, gn_w, gn_b, gamma, xpart, gn2part, out_pre);
    k_out   <<<dim3(512),  dim3(256), 0, stream>>>(out_pre, w_out, gn_w, gn_b, gn2part, outp);
}

// Round 7
// 197.523 us; speedup vs baseline: 1.5648x; 1.5648x over previous
//
#include <hip/hip_runtime.h>
#include <cmath>

// Problem constants (fixed by setup_inputs): B=2, C=1, W=64, H=1024, d=32, WIN=32
#define H_DIM 1024
#define DCH 32
#define WINR 32
#define TQ 256
#define HALO (TQ + 2*WINR)      // 320 staged positions per tile
#define NBLK 512                // 128 rows * 4 tiles

__device__ __forceinline__ float gelu_f(float v) {
    // exact GELU: 0.5*v*(1+erf(v/sqrt(2)))
    return 0.5f * v * (1.0f + erff(v * 0.70710678118654752440f));
}

// float4-chunk XOR swizzle: conflict-free strided writes, uniform reads unaffected
__device__ __forceinline__ int swz(int p, int c) { return p * 8 + (c ^ (p & 7)); }

__device__ __forceinline__ void matvec32(const float* __restrict__ w,
                                         const float zv[DCH], float out[DCH]) {
    // out[e] = sum_d w[e*32+d] * zv[d]; w accesses are wave-uniform -> s_loads
    #pragma unroll
    for (int e = 0; e < DCH; ++e) {
        const float* wr = w + e * DCH;
        float a0 = 0.f, a1 = 0.f, a2 = 0.f, a3 = 0.f;
        #pragma unroll
        for (int d = 0; d < DCH; d += 4) {
            a0 = fmaf(zv[d+0], wr[d+0], a0);
            a1 = fmaf(zv[d+1], wr[d+1], a1);
            a2 = fmaf(zv[d+2], wr[d+2], a2);
            a3 = fmaf(zv[d+3], wr[d+3], a3);
        }
        out[e] = (a0 + a1) + (a2 + a3);
    }
}

__device__ __forceinline__ void write_row(float* buf, int p, const float r[DCH]) {
    #pragma unroll
    for (int c = 0; c < 8; ++c)
        ((float4*)buf)[swz(p, c)] =
            make_float4(r[4*c+0], r[4*c+1], r[4*c+2], r[4*c+3]);
}

// ---------------------------------------------------------------- K1: x partial sums (GN1 stats; feat = x*w_in since C==1)
__global__ __launch_bounds__(256) void k_xstats(const float* __restrict__ x,
                                                double* __restrict__ part) { // [16][2]
    __shared__ double red[8];
    const int b = blockIdx.x;            // 16 blocks, 8 rows each
    const int t = threadIdx.x;
    const float4* px = (const float4*)(x + (size_t)b * 8192);
    double s = 0.0, s2 = 0.0;
    #pragma unroll
    for (int i = 0; i < 8; ++i) {
        float4 v = px[i * 256 + t];
        s  += (double)v.x + (double)v.y + (double)v.z + (double)v.w;
        s2 += (double)v.x*v.x + (double)v.y*v.y + (double)v.z*v.z + (double)v.w*v.w;
    }
    #pragma unroll
    for (int o = 32; o; o >>= 1) { s += __shfl_down(s, o); s2 += __shfl_down(s2, o); }
    if ((t & 63) == 0) { red[(t>>6)*2] = s; red[(t>>6)*2+1] = s2; }
    __syncthreads();
    if (t == 0) {
        part[b*2+0] = red[0]+red[2]+red[4]+red[6];
        part[b*2+1] = red[1]+red[3]+red[5]+red[7];
    }
}

// ---------------------------------------------------------------- K2: fused z->QKV->banded attention->residual
// grid = 512 blocks (128 rows x 4 tiles), 256 threads. LDS 80 KB -> 2 blocks/CU.
__global__ __launch_bounds__(256, 2) void k_main(
    const float* __restrict__ x,
    const float* __restrict__ w_in,
    const float* __restrict__ w_q,
    const float* __restrict__ w_k,
    const float* __restrict__ w_v,
    const float* __restrict__ gn_w,
    const float* __restrict__ gn_b,
    const float* __restrict__ gammap,
    const double* __restrict__ xpart,    // [16][2]
    double* __restrict__ gn2part,        // [512][2]
    float* __restrict__ out_pre)         // [128][1024][32]
{
    __shared__ float ks[HALO * DCH];     // 40 KB
    __shared__ float vs[HALO * DCH];     // 40 KB

    const int t     = threadIdx.x;
    const int bid   = blockIdx.x;
    const int row   = bid >> 2;
    const int tile  = bid & 3;
    const int batch = row >> 6;
    const int h0    = tile * TQ;
    const int g0    = h0 - WINR;

    // ---- GN1 stats from per-block x partials (uniform s_loads) ----
    double Sx = 0.0, Sx2 = 0.0;
    const double* bp = xpart + batch * 16;
    #pragma unroll
    for (int i = 0; i < 8; ++i) { Sx += bp[2*i]; Sx2 += bp[2*i+1]; }
    float sw = 0.f, sw2 = 0.f;
    #pragma unroll
    for (int d = 0; d < DCH; ++d) { float w = w_in[d]; sw += w; sw2 += w*w; }
    const double n1   = 2097152.0;                    // 32*64*1024
    const double mu1d = (double)sw * Sx / n1;
    const double var1 = (double)sw2 * Sx2 / n1 - mu1d * mu1d;
    const float  mu1  = (float)mu1d;
    const float  rstd1 = (float)(1.0 / sqrt(var1 + 1e-5));

    // z = gelu(x * ca[d] + cb[d])
    float ca[DCH], cb[DCH];
    #pragma unroll
    for (int d = 0; d < DCH; ++d) {
        float a = rstd1 * gn_w[d];
        ca[d] = w_in[d] * a;
        cb[d] = gn_b[d] - mu1 * a;
    }

    const float* xrow = x + (size_t)row * H_DIM;

    // ---- staging: thread t owns position p1 = t+32 (h = h0+t, always valid) ----
    const float xq = xrow[h0 + t];
    float q[DCH];
    {
        float zv[DCH];
        #pragma unroll
        for (int d = 0; d < DCH; ++d) zv[d] = gelu_f(fmaf(xq, ca[d], cb[d]));
        float kr[DCH], vr[DCH];
        matvec32(w_k, zv, kr);
        matvec32(w_v, zv, vr);
        write_row(ks, t + WINR, kr);
        write_row(vs, t + WINR, vr);
        matvec32(w_q, zv, q);
        #pragma unroll
        for (int e = 0; e < DCH; ++e) q[e] *= 0.17677669529663688f; // 1/sqrt(32)
    }
    // halo positions 0..31 and 288..319: wave 0 only (waves 1-3 skip via execz)
    if (t < 64) {
        const int p0 = (t < 32) ? t : (256 + t);
        const int h  = g0 + p0;
        const float xv = ((unsigned)h < H_DIM) ? xrow[h] : 0.f;
        float zv[DCH];
        #pragma unroll
        for (int d = 0; d < DCH; ++d) zv[d] = gelu_f(fmaf(xv, ca[d], cb[d]));
        float kr[DCH], vr[DCH];
        matvec32(w_k, zv, kr);
        matvec32(w_v, zv, vr);
        write_row(ks, p0, kr);
        write_row(vs, p0, vr);
    }
    __syncthreads();

    // ---- attention: wave-uniform key broadcast, CHUNKED online softmax ----
    // Chunk of 8 keys: 8 scores (branch-free, deep ILP) -> 1 max tree ->
    // 1 rescale vote -> 8 exp + PV. m starts at -80 so invalid keys
    // (sc=-3e38) give exp(sc-m)=0 with NO per-key valid cndmask in PV.
    // Safety: self-key score = |q|^2*scale >= 0 > -72, so the chunk holding
    // it always triggers the rescale vote before pw can overflow; pw <= e^8.
    const int lane  = t & 63;
    const int wid   = t >> 6;
    const int pbase = wid * 64;          // wave's first key slot
    const int jbase = g0 + pbase;        // global h of that slot

    float m = -80.0f, l = 0.f;
    float o[DCH];
    #pragma unroll
    for (int d = 0; d < DCH; ++d) o[d] = 0.f;

    #pragma unroll 2
    for (int ch = 0; ch < 16; ++ch) {
        float sc[8];
        // ---- score phase: 8 keys, no branches ----
        #pragma unroll
        for (int u = 0; u < 8; ++u) {
            const int kk = ch * 8 + u;
            const int p  = pbase + kk;
            const int pm = p & 7;
            const float4* kb = (const float4*)ks + p * 8;
            float a0 = 0.f, a1 = 0.f, a2 = 0.f, a3 = 0.f;
            #pragma unroll
            for (int c = 0; c < 8; ++c) {
                float4 k4 = kb[c ^ pm];          // uniform address: broadcast
                a0 = fmaf(q[4*c+0], k4.x, a0);
                a1 = fmaf(q[4*c+1], k4.y, a1);
                a2 = fmaf(q[4*c+2], k4.z, a2);
                a3 = fmaf(q[4*c+3], k4.w, a3);
            }
            const float s = (a0 + a1) + (a2 + a3);
            const bool valid = ((unsigned)(kk - lane) <= 64u) &&
                               ((unsigned)(jbase + kk) < (unsigned)H_DIM);
            sc[u] = valid ? s : -3.0e38f;
        }
        // ---- chunk max tree (7 ops) ----
        const float c01 = fmaxf(sc[0], sc[1]);
        const float c23 = fmaxf(sc[2], sc[3]);
        const float c45 = fmaxf(sc[4], sc[5]);
        const float c67 = fmaxf(sc[6], sc[7]);
        const float cmax = fmaxf(fmaxf(c01, c23), fmaxf(c45, c67));
        // ---- one rescale vote per chunk (defer-max, THR=8) ----
        if (__any(cmax > m + 8.0f)) {
            const float mn = fmaxf(m, cmax);     // per-lane
            const float corr = __expf(m - mn);
            l *= corr;
            #pragma unroll
            for (int d = 0; d < DCH; ++d) o[d] *= corr;
            m = mn;
        }
        // ---- exp + PV phase: 8 keys, branch-free ----
        #pragma unroll
        for (int u = 0; u < 8; ++u) {
            const float pw = __expf(sc[u] - m);  // 0 for invalid keys
            l += pw;
            const int p  = pbase + ch * 8 + u;
            const int pm = p & 7;
            const float4* vb = (const float4*)vs + p * 8;
            #pragma unroll
            for (int c = 0; c < 8; ++c) {
                float4 v4 = vb[c ^ pm];          // broadcast read
                o[4*c+0] = fmaf(pw, v4.x, o[4*c+0]);
                o[4*c+1] = fmaf(pw, v4.y, o[4*c+1]);
                o[4*c+2] = fmaf(pw, v4.z, o[4*c+2]);
                o[4*c+3] = fmaf(pw, v4.w, o[4*c+3]);
            }
        }
    }
    const float inv = 1.0f / l;

    // ---- epilogue: out_pre = feat + gamma*o, GN2 per-block partials ----
    const float gamma = gammap[0];
    float so = 0.f, so2 = 0.f;
    float* op = out_pre + ((size_t)row * H_DIM + (h0 + t)) * DCH;
    #pragma unroll
    for (int c = 0; c < 8; ++c) {
        float4 wi4 = ((const float4*)w_in)[c];
        float4 r;
        r.x = fmaf(gamma, o[4*c+0] * inv, xq * wi4.x);
        r.y = fmaf(gamma, o[4*c+1] * inv, xq * wi4.y);
        r.z = fmaf(gamma, o[4*c+2] * inv, xq * wi4.z);
        r.w = fmaf(gamma, o[4*c+3] * inv, xq * wi4.w);
        ((float4*)op)[c] = r;
        so  += r.x + r.y + r.z + r.w;
        so2 += r.x*r.x + r.y*r.y + r.z*r.z + r.w*r.w;
    }
    double ds = (double)so, ds2 = (double)so2;
    #pragma unroll
    for (int ofs = 32; ofs; ofs >>= 1) {
        ds  += __shfl_down(ds, ofs);
        ds2 += __shfl_down(ds2, ofs);
    }
    __syncthreads();                      // all LDS attention reads done
    double* red = (double*)ks;            // reuse LDS (no extra static shared!)
    if (lane == 0) { red[wid*2] = ds; red[wid*2+1] = ds2; }
    __syncthreads();
    if (t == 0) {
        gn2part[bid*2+0] = red[0]+red[2]+red[4]+red[6];
        gn2part[bid*2+1] = red[1]+red[3]+red[5]+red[7];
    }
}

// ---------------------------------------------------------------- K3: GN2 + gelu + out-projection
__global__ __launch_bounds__(256) void k_out(
    const float* __restrict__ out_pre,
    const float* __restrict__ w_out,
    const float* __restrict__ gn_w,
    const float* __restrict__ gn_b,
    const double* __restrict__ gn2part,  // [512][2]
    float* __restrict__ outp)
{
    __shared__ double red[8];
    const int t   = threadIdx.x;
    const int bid = blockIdx.x;
    const int batch = bid >> 8;          // uniform per block

    // reduce this batch's 256 partial pairs across the block
    const double* gp = gn2part + (size_t)batch * 512;
    double ds = gp[2*t], ds2 = gp[2*t+1];
    #pragma unroll
    for (int ofs = 32; ofs; ofs >>= 1) {
        ds  += __shfl_down(ds, ofs);
        ds2 += __shfl_down(ds2, ofs);
    }
    if ((t & 63) == 0) { red[(t>>6)*2] = ds; red[(t>>6)*2+1] = ds2; }
    __syncthreads();
    const double S  = red[0]+red[2]+red[4]+red[6];
    const double S2 = red[1]+red[3]+red[5]+red[7];
    const double n2 = 2097152.0;
    const double mu = S / n2;
    const double var = S2 / n2 - mu * mu;
    const float muf  = (float)mu;
    const float rstd = (float)(1.0 / sqrt(var + 1e-5));

    const int pix = bid * 256 + t;
    const float4* ip = (const float4*)(out_pre + (size_t)pix * DCH);
    float acc_o = 0.f;
    #pragma unroll
    for (int c = 0; c < 8; ++c) {
        float4 v  = ip[c];
        float4 gw = ((const float4*)gn_w)[c];
        float4 gb = ((const float4*)gn_b)[c];
        float4 wo = ((const float4*)w_out)[c];
        acc_o += gelu_f((v.x - muf) * rstd * gw.x + gb.x) * wo.x;
        acc_o += gelu_f((v.y - muf) * rstd * gw.y + gb.y) * wo.y;
        acc_o += gelu_f((v.z - muf) * rstd * gw.z + gb.z) * wo.z;
        acc_o += gelu_f((v.w - muf) * rstd * gw.w + gb.w) * wo.w;
    }
    outp[pix] = acc_o;
}

// ---------------------------------------------------------------- launch
extern "C" void kernel_launch(void* const* d_in, const int* in_sizes, int n_in,
                              void* d_out, int out_size, void* d_ws, size_t ws_size,
                              hipStream_t stream) {
    const float* x     = (const float*)d_in[0];
    const float* w_in  = (const float*)d_in[1];
    const float* w_q   = (const float*)d_in[2];
    const float* w_k   = (const float*)d_in[3];
    const float* w_v   = (const float*)d_in[4];
    const float* w_out = (const float*)d_in[5];
    const float* gn_w  = (const float*)d_in[6];
    const float* gn_b  = (const float*)d_in[7];
    const float* gamma = (const float*)d_in[8];

    double* xpart   = (double*)d_ws;                          // 32 doubles
    double* gn2part = (double*)((char*)d_ws + 256);           // 1024 doubles
    float*  out_pre = (float*)((char*)d_ws + 8448);           // 16.78 MB
    float*  outp    = (float*)d_out;

    k_xstats<<<dim3(16),   dim3(256), 0, stream>>>(x, xpart);
    k_main  <<<dim3(NBLK), dim3(256), 0, stream>>>(
        x, w_in, w_q, w_k, w_v, gn_w, gn_b, gamma, xpart, gn2part, out_pre);
    k_out   <<<dim3(512),  dim3(256), 0, stream>>>(out_pre, w_out, gn_w, gn_b, gn2part, outp);
}